// Round 3
// baseline (278.976 us; speedup 1.0000x reference)
//
#include <hip/hip_runtime.h>
#include <stdint.h>

typedef unsigned short u16;
typedef __attribute__((ext_vector_type(8))) short bf16x8;   // 8 bf16 in 4 VGPRs
typedef __attribute__((ext_vector_type(4))) float floatx4;

#define MFMA16(a, b, c) __builtin_amdgcn_mfma_f32_16x16x32_bf16(a, b, c, 0, 0, 0)
#define MEMFENCE asm volatile("" ::: "memory")

#if __has_builtin(__builtin_amdgcn_exp2f)
#define EXP2(x) __builtin_amdgcn_exp2f(x)
#else
#define EXP2(x) __expf(0.6931471805599453f * (x))
#endif

__device__ __forceinline__ u16 f2bf(float f) {   // round-to-nearest-even
  unsigned u = __builtin_bit_cast(unsigned, f);
  return (u16)((u + 0x7FFFu + ((u >> 16) & 1u)) >> 16);
}
__device__ __forceinline__ u16 f2bf_hu(float f) {  // round-half-up (cheaper)
  return (u16)((__builtin_bit_cast(unsigned, f) + 0x8000u) >> 16);
}
__device__ __forceinline__ float bf2f(u16 v) {
  return __builtin_bit_cast(float, (unsigned)v << 16);
}

// async global->LDS, 16B/lane. LDS dest = wave-uniform base + lane*16 (HW).
__device__ __forceinline__ void glds16(void* lds, const void* g) {
  __builtin_amdgcn_global_load_lds((const __attribute__((address_space(1))) void*)g,
                                   (__attribute__((address_space(3))) void*)lds,
                                   16, 0, 0);
}

// ---------------------------------------------------------------- convert
__global__ __launch_bounds__(256) void cvt_all(
    const float* __restrict__ x, const float* __restrict__ w0,
    const float* __restrict__ w1, const float* __restrict__ w2,
    u16* __restrict__ xb, u16* __restrict__ Wb) {
  const int bid = blockIdx.x;
  const float* src;
  u16* dst;
  int i;
  if (bid < 4096) {
    src = x; dst = xb; i = bid * 256 + threadIdx.x;
  } else {
    const int z = (bid - 4096) >> 10;
    src = (z == 0) ? w0 : (z == 1) ? w1 : w2;
    dst = Wb + (size_t)z * (1024 * 1024);
    i = ((bid - 4096) & 1023) * 256 + threadIdx.x;
  }
  float4 f = reinterpret_cast<const float4*>(src)[i];
  ushort4 o;
  o.x = f2bf(f.x); o.y = f2bf(f.y); o.z = f2bf(f.z); o.w = f2bf(f.w);
  reinterpret_cast<ushort4*>(dst)[i] = o;
}

// ---------------------------------------------------------------- QKV GEMM
// (unchanged, proven) C[m,n] = sum_k x[m,k]*W[n,k] + bias[n].
__global__ __launch_bounds__(256, 3) void qkv_gemm(
    const u16* __restrict__ xb, const u16* __restrict__ Wb,
    const float* __restrict__ bq, const float* __restrict__ bk,
    const float* __restrict__ bv,
    u16* __restrict__ Qb, u16* __restrict__ Kb, u16* __restrict__ VTb) {
  __shared__ __attribute__((aligned(16))) u16 smem[2 * 128 * 64];   // 32KB
  u16* As = smem;
  u16* Bs = smem + 128 * 64;

  const int tid = threadIdx.x;
  const int w = tid >> 6, lane = tid & 63;
  const int lo = lane & 15, quad = lane >> 4;
  const int which = blockIdx.z;
  const int m0 = blockIdx.x * 128, n0 = blockIdx.y * 128;

  const u16* W = Wb + (size_t)which * (1024 * 1024);
  const int wm = (w >> 1) * 64, wn = (w & 1) * 64;

  floatx4 acc[4][4];
  for (int i = 0; i < 4; ++i)
    for (int j = 0; j < 4; ++j) acc[i][j] = (floatx4)0.f;

  const int arow = lane >> 3;                 // 0..7 within 8-row segment
  const int aswz = ((lane & 7) ^ arow) * 8;   // swizzled global col chunk

  for (int kt = 0; kt < 16; ++kt) {
    const int k0 = kt * 64;
    for (int j = 0; j < 4; ++j) {
      const int seg = w * 4 + j;              // 16 segs of 8 rows each side
      glds16(As + seg * 512, xb + (size_t)(m0 + seg * 8 + arow) * 1024 + k0 + aswz);
      glds16(Bs + seg * 512, W + (size_t)(n0 + seg * 8 + arow) * 1024 + k0 + aswz);
    }
    __syncthreads();
    for (int kk = 0; kk < 2; ++kk) {
      const int swz = ((kk * 4 + quad) ^ (lo & 7)) * 8;
      bf16x8 af[4], bfr[4];
      for (int it = 0; it < 4; ++it)
        af[it] = *reinterpret_cast<const bf16x8*>(As + (wm + it * 16 + lo) * 64 + swz);
      for (int jt = 0; jt < 4; ++jt)
        bfr[jt] = *reinterpret_cast<const bf16x8*>(Bs + (wn + jt * 16 + lo) * 64 + swz);
      for (int it = 0; it < 4; ++it)
        for (int jt = 0; jt < 4; ++jt)
          acc[it][jt] = MFMA16(af[it], bfr[jt], acc[it][jt]);
    }
    __syncthreads();
  }

  const float* bias = (which == 0) ? bq : (which == 1) ? bk : bv;
  float bb[4];
  for (int jt = 0; jt < 4; ++jt) bb[jt] = bias[n0 + wn + jt * 16 + lo];
  const int b = m0 >> 11;

  if (which < 2) {
    // per-wave 16x64 transpose tiles (pad->72, swizzled)
    const float scl = (which == 0) ? 0.36067376022224085f : 1.0f;  // 0.25*log2e
    u16* Tw = smem + w * (16 * 72);
    const int hblk = (n0 + wn) >> 6;
    u16* dst = ((which == 0) ? Qb : Kb) +
               ((size_t)(b * 16 + hblk) * 2048 + ((m0 & 2047) + wm)) * 64;
    for (int it = 0; it < 4; ++it) {
      for (int jt = 0; jt < 4; ++jt)
        for (int r = 0; r < 4; ++r) {
          const int m = quad * 4 + r, col = jt * 16 + lo;
          Tw[m * 72 + (((col >> 3) ^ (m & 7)) * 8) + (col & 7)] =
              f2bf((acc[it][jt][r] + bb[jt]) * scl);
        }
      MEMFENCE;   // scalar u16 writes -> vector reads, same wave: keep order
      for (int rd = 0; rd < 2; ++rd) {   // per-wave in-order DS: no barrier
        const int sr = rd * 8 + (lane >> 3), d8 = lane & 7;
        bf16x8 v = *reinterpret_cast<const bf16x8*>(Tw + sr * 72 + ((d8 ^ (sr & 7)) * 8));
        *reinterpret_cast<bf16x8*>(dst + (size_t)(it * 16 + sr) * 64 + d8 * 8) = v;
      }
      MEMFENCE;   // vector reads done before next it overwrites Tw
    }
  } else {
    // V^T: block transpose [128 n][64 m] (pad->72) in two m-passes.
    for (int pass = 0; pass < 2; ++pass) {
      if ((wm >> 6) == pass) {
        for (int it = 0; it < 4; ++it)
          for (int jt = 0; jt < 4; ++jt)
            for (int r = 0; r < 4; ++r) {
              const int n = wn + jt * 16 + lo;
              const int m = it * 16 + quad * 4 + r;   // local 0..63
              smem[n * 72 + (((m >> 3) ^ (n & 7)) * 8) + (m & 7)] =
                  f2bf(acc[it][jt][r] + bb[jt]);
            }
      }
      __syncthreads();
      for (int rd = 0; rd < 4; ++rd) {
        const int n = (tid >> 3) + rd * 32, m8 = tid & 7;
        bf16x8 v = *reinterpret_cast<const bf16x8*>(smem + n * 72 + ((m8 ^ (n & 7)) * 8));
        const int ng = n0 + n, h = ng >> 6, d = ng & 63;
        const int s = (m0 & 2047) + pass * 64 + m8 * 8;
        *reinterpret_cast<bf16x8*>(VTb + ((size_t)(b * 16 + h) * 64 + d) * 2048 + s) = v;
      }
      __syncthreads();
    }
  }
}

// ---------------------------------------------------------------- attention
// R3: split-K, barrier-free, L2-direct operands.
// Counters (R0/R1/R2) show all pipes <20% busy at 13% occupancy: latency-
// chain bound, grid-capped at 2 blocks/CU. This softmax has NO running max
// (pure exp2 accumulation), so the key range splits freely into independent
// partial blocks. Grid: 32 items x 32 bh = 1024 blocks; item i: qs=i>>1,
// h=i&1, tiles [2qs + h*(16-qs), 2qs + (h+1)*(16-qs)). No K/V in LDS: K and
// V fragments load straight from L2 (addresses verified equal to the staged
// path's net layout; V form proven in R2). K is register-prefetched one tile
// ahead -> compiler emits counted vmcnt (no barrier ever drains to 0: there
// are NO barriers). LDS = Pt only (16KB). (256,3) -> 12 waves/CU, +50% fill.
// h=0 writes unnormalized f32 acc to out + l0; h=1 writes bf16 acc to the
// dead xb region + l1; combine sums & normalizes; fix2047 runs last.
__global__ __launch_bounds__(256, 3) void attn(
    const u16* __restrict__ Qb, const u16* __restrict__ Kb,
    const u16* __restrict__ VTb, float* __restrict__ out,
    u16* __restrict__ acc1, float* __restrict__ l0, float* __restrict__ l1) {
  __shared__ __attribute__((aligned(16))) u16 Pt[4][2][16 * 64];  // per-wave/qset

  const int blk = blockIdx.x;               // 1024 blocks, longest items first
  const int bh = blk & 31;                  // bh%8 -> spread across XCDs
  const int item = blk >> 5;                // 0..31
  const int qs = item >> 1, h = item & 1;   // supertile + key-half
  const int Lh = 16 - qs;                   // tiles in this half
  const int kstart = 2 * qs + h * Lh;
  const int kend = kstart + Lh;

  const int tid = threadIdx.x, w = tid >> 6, lane = tid & 63;
  const int lo = lane & 15, quad = lane >> 4;

  const u16* Qh = Qb + (size_t)bh * (2048 * 64);
  const u16* Kh = Kb + (size_t)bh * (2048 * 64);
  const u16* Vh = VTb + (size_t)bh * (64 * 2048);

  int qrow[2];
  bf16x8 qf[2][2];
  for (int s = 0; s < 2; ++s) {
    qrow[s] = qs * 128 + w * 32 + s * 16 + lo;
    qf[s][0] = *reinterpret_cast<const bf16x8*>(Qh + (size_t)qrow[s] * 64 + quad * 8);
    qf[s][1] = *reinterpret_cast<const bf16x8*>(Qh + (size_t)qrow[s] * 64 + 32 + quad * 8);
  }

  float lrun[2] = {0.f, 0.f};
  floatx4 acc[2][4];
  for (int s = 0; s < 2; ++s)
    for (int dt = 0; dt < 4; ++dt) acc[s][dt] = (floatx4)0.f;

  // K fragments for tile kstart, direct from L2 into registers.
  // ka[kk*4+t] = K[kt*64 + t*16 + lo][kk*32 + quad*8 .. +7]
  bf16x8 kfr[8];
  {
    const u16* kp = Kh + (size_t)kstart * (64 * 64) + (size_t)lo * 64 + quad * 8;
    for (int kk = 0; kk < 2; ++kk)
      for (int t = 0; t < 4; ++t)
        kfr[kk * 4 + t] = *reinterpret_cast<const bf16x8*>(kp + t * 16 * 64 + kk * 32);
  }

  for (int kt = kstart; kt < kend; ++kt) {
    const int d2 = kt - 2 * qs;     // position vs supertile diagonal
    const bool skip = (d2 == 0) && (w >= 2);
    const bool maskp = ((d2 == 0) && (w < 2)) || ((d2 == 1) && (w >= 2));

    // V fragments direct from L2 (issued at tile top; used in PV ~400cy later)
    bf16x8 vfrag[2][4];
    if (!skip) {
      for (int kk = 0; kk < 2; ++kk)
        for (int dt = 0; dt < 4; ++dt)
          vfrag[kk][dt] = *reinterpret_cast<const bf16x8*>(
              Vh + (size_t)(dt * 16 + lo) * 2048 + kt * 64 + kk * 32 + quad * 8);
    }

    floatx4 sc[2][4];
    if (!skip) {
      for (int s = 0; s < 2; ++s)
        for (int t = 0; t < 4; ++t) sc[s][t] = (floatx4)0.f;
      for (int kk = 0; kk < 2; ++kk)
        for (int t = 0; t < 4; ++t) {
          sc[0][t] = MFMA16(kfr[kk * 4 + t], qf[0][kk], sc[0][t]);
          sc[1][t] = MFMA16(kfr[kk * 4 + t], qf[1][kk], sc[1][t]);
        }
    }

    // register-prefetch next K tile (kfr just consumed; loads fill during
    // exp/PV -> compiler emits counted vmcnt, no stall)
    {
      const int ktn = (kt + 1 < kend) ? kt + 1 : kt;
      const u16* kp = Kh + (size_t)ktn * (64 * 64) + (size_t)lo * 64 + quad * 8;
      for (int kk = 0; kk < 2; ++kk)
        for (int t = 0; t < 4; ++t)
          kfr[kk * 4 + t] = *reinterpret_cast<const bf16x8*>(kp + t * 16 * 64 + kk * 32);
    }

    if (!skip) {
      for (int s = 0; s < 2; ++s) {
        u16* ptw = &Pt[w][s][0];
        for (int t = 0; t < 4; ++t) {
          float p0 = EXP2(sc[s][t][0]), p1 = EXP2(sc[s][t][1]);
          float p2 = EXP2(sc[s][t][2]), p3 = EXP2(sc[s][t][3]);
          if (maskp) {   // keep key > q (faithful buggy mask)
            const int key = kt * 64 + t * 16 + quad * 4;
            p0 = (key + 0 > qrow[s]) ? p0 : 0.f;
            p1 = (key + 1 > qrow[s]) ? p1 : 0.f;
            p2 = (key + 2 > qrow[s]) ? p2 : 0.f;
            p3 = (key + 3 > qrow[s]) ? p3 : 0.f;
          }
          lrun[s] += (p0 + p1) + (p2 + p3);
          ushort4 pk;   // short-family store: aliases the bf16x8 read below
          pk.x = f2bf_hu(p0); pk.y = f2bf_hu(p1);
          pk.z = f2bf_hu(p2); pk.w = f2bf_hu(p3);
          u16* pdst = ptw + lo * 64 +
                      (((2 * t + (quad >> 1)) ^ (lo & 7)) * 8) + (quad & 1) * 4;
          *reinterpret_cast<ushort4*>(pdst) = pk;
        }
      }
      MEMFENCE;   // Pt writes ordered before PV reads (same wave, in-order DS)

      for (int kk = 0; kk < 2; ++kk) {   // O^T += V^T * P^T, V from VGPRs
        const int pswz = ((kk * 4 + quad) ^ (lo & 7)) * 8;
        bf16x8 pb0 = *reinterpret_cast<const bf16x8*>(&Pt[w][0][lo * 64] + pswz);
        bf16x8 pb1 = *reinterpret_cast<const bf16x8*>(&Pt[w][1][lo * 64] + pswz);
        for (int dt = 0; dt < 4; ++dt) {
          acc[0][dt] = MFMA16(vfrag[kk][dt], pb0, acc[0][dt]);
          acc[1][dt] = MFMA16(vfrag[kk][dt], pb1, acc[1][dt]);
        }
      }
      MEMFENCE;   // Pt reads done before next tile overwrites (same wave)
    }
  }

  const int b = bh >> 4, hh = bh & 15;
  for (int s = 0; s < 2; ++s) {
    float l = lrun[s];
    l += __shfl_xor(l, 16);
    l += __shfl_xor(l, 32);
    if (h == 0) {
      // unnormalized f32 partial straight into out (combine divides later)
      float* op = out + ((size_t)(b * 2048 + qrow[s])) * 1024 + hh * 64 + quad * 4;
      for (int dt = 0; dt < 4; ++dt) {
        float4 o4;
        o4.x = acc[s][dt][0]; o4.y = acc[s][dt][1];
        o4.z = acc[s][dt][2]; o4.w = acc[s][dt][3];
        *reinterpret_cast<float4*>(op + dt * 16) = o4;
      }
      if (quad == 0) l0[(size_t)bh * 2048 + qrow[s]] = l;
    } else {
      // bf16 partial into dead xb region (RNE rounding, unbiased)
      u16* ap = acc1 + ((size_t)bh * 2048 + qrow[s]) * 64 + quad * 4;
      for (int dt = 0; dt < 4; ++dt) {
        ushort4 a4;
        a4.x = f2bf(acc[s][dt][0]); a4.y = f2bf(acc[s][dt][1]);
        a4.z = f2bf(acc[s][dt][2]); a4.w = f2bf(acc[s][dt][3]);
        *reinterpret_cast<ushort4*>(ap + dt * 16) = a4;
      }
      if (quad == 0) l1[(size_t)bh * 2048 + qrow[s]] = l;
    }
  }
}

// ---------------------------------------------------------------- combine
// out = (acc0 + acc1) / (l0 + l1); skips rows with l==0 (row 2047 -> fix2047).
__global__ __launch_bounds__(256) void combine(
    float* __restrict__ out, const u16* __restrict__ acc1,
    const float* __restrict__ l0, const float* __restrict__ l1) {
  const int R = blockIdx.x;          // 0..4095 = b*2048 + q
  const int c4 = threadIdx.x;        // float4 index within 1024-col row
  const int hd = c4 >> 4;            // head 0..15
  const int b = R >> 11, q = R & 2047;
  const size_t bhq = (size_t)(b * 16 + hd) * 2048 + q;
  const float ls = l0[bhq] + l1[bhq];
  if (ls == 0.f) return;             // fully-masked row 2047 (fix2047 covers)
  const float rl = 1.f / ls;
  float4* o4 = reinterpret_cast<float4*>(out) + (size_t)R * 256 + c4;
  float4 o = *o4;
  const ushort4 a = reinterpret_cast<const ushort4*>(acc1)[bhq * 16 + (c4 & 15)];
  o.x = (o.x + bf2f(a.x)) * rl;
  o.y = (o.y + bf2f(a.y)) * rl;
  o.z = (o.z + bf2f(a.z)) * rl;
  o.w = (o.w + bf2f(a.w)) * rl;
  *o4 = o;
}

// ---------------------------------------------------------------- fix2047
// Row 2047 fully masked -> uniform softmax: out = mean_s V[b,s,:].
__global__ __launch_bounds__(256) void fix2047(const u16* __restrict__ VTb,
                                               float* __restrict__ out) {
  const int bh = blockIdx.x;
  const u16* Vh = VTb + (size_t)bh * (64 * 2048);
  const int t = threadIdx.x;
  const int d = t >> 2, j = t & 3;
  float s = 0.f;
  const u16* row = Vh + (size_t)d * 2048 + j * 512;
  for (int i = 0; i < 64; ++i) {
    bf16x8 v = *reinterpret_cast<const bf16x8*>(row + i * 8);
    for (int e = 0; e < 8; ++e) s += bf2f((u16)v[e]);
  }
  s += __shfl_xor(s, 1);
  s += __shfl_xor(s, 2);
  if (j == 0) {
    const int b = bh >> 4, h = bh & 15;
    out[((size_t)(b * 2048 + 2047)) * 1024 + h * 64 + d] = s * (1.f / 2048.f);
  }
}

// ---------------------------------------------------------------- launch
extern "C" void kernel_launch(void* const* d_in, const int* in_sizes, int n_in,
                              void* d_out, int out_size, void* d_ws, size_t ws_size,
                              hipStream_t stream) {
  const float* x  = (const float*)d_in[0];
  const float* Wq = (const float*)d_in[1];
  const float* bq = (const float*)d_in[2];
  const float* Wk = (const float*)d_in[3];
  const float* bk = (const float*)d_in[4];
  const float* Wv = (const float*)d_in[5];
  const float* bv = (const float*)d_in[6];
  float* out = (float*)d_out;

  char* ws = (char*)d_ws;
  u16* xb  = (u16*)(ws);                  // 8 MB: x as bf16 [4096][1024]
  u16* Wb  = (u16*)(ws + (8u << 20));     // 6 MB: Wq,Wk,Wv bf16
  u16* Qb  = (u16*)(ws + (14u << 20));    // 8 MB: Q  [B,H,S,dh] (pre-scaled)
  u16* Kb  = (u16*)(ws + (22u << 20));    // 8 MB: K  [B,H,S,dh]
  u16* VTb = (u16*)(ws + (30u << 20));    // 8 MB: V^T [B,H,dh,S]
  // partials reuse the xb/Wb region (dead after qkv_gemm):
  u16*   acc1 = (u16*)(ws);                           // 8 MB bf16 [32][2048][64]
  float* l0   = (float*)(ws + (8u << 20));            // 256 KB [32][2048]
  float* l1   = (float*)(ws + (8u << 20) + (256u << 10));

  cvt_all<<<7168, 256, 0, stream>>>(x, Wq, Wk, Wv, xb, Wb);
  qkv_gemm<<<dim3(32, 8, 3), 256, 0, stream>>>(xb, Wb, bq, bk, bv, Qb, Kb, VTb);
  attn<<<dim3(1024), 256, 0, stream>>>(Qb, Kb, VTb, out, acc1, l0, l1);
  combine<<<dim3(4096), 256, 0, stream>>>(out, acc1, l0, l1);
  fix2047<<<dim3(32), 256, 0, stream>>>(VTb, out);
}

// Round 4
// 151.480 us; speedup vs baseline: 1.8417x; 1.8417x over previous
//
#include <hip/hip_runtime.h>
#include <stdint.h>

typedef unsigned short u16;
typedef __attribute__((ext_vector_type(8))) short bf16x8;   // 8 bf16 in 4 VGPRs
typedef __attribute__((ext_vector_type(4))) float floatx4;

#define MFMA16(a, b, c) __builtin_amdgcn_mfma_f32_16x16x32_bf16(a, b, c, 0, 0, 0)
#define MEMFENCE asm volatile("" ::: "memory")

#if __has_builtin(__builtin_amdgcn_exp2f)
#define EXP2(x) __builtin_amdgcn_exp2f(x)
#else
#define EXP2(x) __expf(0.6931471805599453f * (x))
#endif

__device__ __forceinline__ u16 f2bf(float f) {   // round-to-nearest-even
  unsigned u = __builtin_bit_cast(unsigned, f);
  return (u16)((u + 0x7FFFu + ((u >> 16) & 1u)) >> 16);
}
__device__ __forceinline__ u16 f2bf_hu(float f) {  // round-half-up (cheaper)
  return (u16)((__builtin_bit_cast(unsigned, f) + 0x8000u) >> 16);
}
__device__ __forceinline__ float bf2f(u16 v) {
  return __builtin_bit_cast(float, (unsigned)v << 16);
}

// async global->LDS, 16B/lane. LDS dest = wave-uniform base + lane*16 (HW).
__device__ __forceinline__ void glds16(void* lds, const void* g) {
  __builtin_amdgcn_global_load_lds((const __attribute__((address_space(1))) void*)g,
                                   (__attribute__((address_space(3))) void*)lds,
                                   16, 0, 0);
}

// ---------------------------------------------------------------- convert
__global__ __launch_bounds__(256) void cvt_all(
    const float* __restrict__ x, const float* __restrict__ w0,
    const float* __restrict__ w1, const float* __restrict__ w2,
    u16* __restrict__ xb, u16* __restrict__ Wb) {
  const int bid = blockIdx.x;
  const float* src;
  u16* dst;
  int i;
  if (bid < 4096) {
    src = x; dst = xb; i = bid * 256 + threadIdx.x;
  } else {
    const int z = (bid - 4096) >> 10;
    src = (z == 0) ? w0 : (z == 1) ? w1 : w2;
    dst = Wb + (size_t)z * (1024 * 1024);
    i = ((bid - 4096) & 1023) * 256 + threadIdx.x;
  }
  float4 f = reinterpret_cast<const float4*>(src)[i];
  ushort4 o;
  o.x = f2bf(f.x); o.y = f2bf(f.y); o.z = f2bf(f.z); o.w = f2bf(f.w);
  reinterpret_cast<ushort4*>(dst)[i] = o;
}

// ---------------------------------------------------------------- QKV GEMM
// (unchanged, proven) C[m,n] = sum_k x[m,k]*W[n,k] + bias[n].
__global__ __launch_bounds__(256, 3) void qkv_gemm(
    const u16* __restrict__ xb, const u16* __restrict__ Wb,
    const float* __restrict__ bq, const float* __restrict__ bk,
    const float* __restrict__ bv,
    u16* __restrict__ Qb, u16* __restrict__ Kb, u16* __restrict__ VTb) {
  __shared__ __attribute__((aligned(16))) u16 smem[2 * 128 * 64];   // 32KB
  u16* As = smem;
  u16* Bs = smem + 128 * 64;

  const int tid = threadIdx.x;
  const int w = tid >> 6, lane = tid & 63;
  const int lo = lane & 15, quad = lane >> 4;
  const int which = blockIdx.z;
  const int m0 = blockIdx.x * 128, n0 = blockIdx.y * 128;

  const u16* W = Wb + (size_t)which * (1024 * 1024);
  const int wm = (w >> 1) * 64, wn = (w & 1) * 64;

  floatx4 acc[4][4];
  for (int i = 0; i < 4; ++i)
    for (int j = 0; j < 4; ++j) acc[i][j] = (floatx4)0.f;

  const int arow = lane >> 3;                 // 0..7 within 8-row segment
  const int aswz = ((lane & 7) ^ arow) * 8;   // swizzled global col chunk

  for (int kt = 0; kt < 16; ++kt) {
    const int k0 = kt * 64;
    for (int j = 0; j < 4; ++j) {
      const int seg = w * 4 + j;              // 16 segs of 8 rows each side
      glds16(As + seg * 512, xb + (size_t)(m0 + seg * 8 + arow) * 1024 + k0 + aswz);
      glds16(Bs + seg * 512, W + (size_t)(n0 + seg * 8 + arow) * 1024 + k0 + aswz);
    }
    __syncthreads();
    for (int kk = 0; kk < 2; ++kk) {
      const int swz = ((kk * 4 + quad) ^ (lo & 7)) * 8;
      bf16x8 af[4], bfr[4];
      for (int it = 0; it < 4; ++it)
        af[it] = *reinterpret_cast<const bf16x8*>(As + (wm + it * 16 + lo) * 64 + swz);
      for (int jt = 0; jt < 4; ++jt)
        bfr[jt] = *reinterpret_cast<const bf16x8*>(Bs + (wn + jt * 16 + lo) * 64 + swz);
      for (int it = 0; it < 4; ++it)
        for (int jt = 0; jt < 4; ++jt)
          acc[it][jt] = MFMA16(af[it], bfr[jt], acc[it][jt]);
    }
    __syncthreads();
  }

  const float* bias = (which == 0) ? bq : (which == 1) ? bk : bv;
  float bb[4];
  for (int jt = 0; jt < 4; ++jt) bb[jt] = bias[n0 + wn + jt * 16 + lo];
  const int b = m0 >> 11;

  if (which < 2) {
    // per-wave 16x64 transpose tiles (pad->72, swizzled)
    const float scl = (which == 0) ? 0.36067376022224085f : 1.0f;  // 0.25*log2e
    u16* Tw = smem + w * (16 * 72);
    const int hblk = (n0 + wn) >> 6;
    u16* dst = ((which == 0) ? Qb : Kb) +
               ((size_t)(b * 16 + hblk) * 2048 + ((m0 & 2047) + wm)) * 64;
    for (int it = 0; it < 4; ++it) {
      for (int jt = 0; jt < 4; ++jt)
        for (int r = 0; r < 4; ++r) {
          const int m = quad * 4 + r, col = jt * 16 + lo;
          Tw[m * 72 + (((col >> 3) ^ (m & 7)) * 8) + (col & 7)] =
              f2bf((acc[it][jt][r] + bb[jt]) * scl);
        }
      MEMFENCE;   // scalar u16 writes -> vector reads, same wave: keep order
      for (int rd = 0; rd < 2; ++rd) {   // per-wave in-order DS: no barrier
        const int sr = rd * 8 + (lane >> 3), d8 = lane & 7;
        bf16x8 v = *reinterpret_cast<const bf16x8*>(Tw + sr * 72 + ((d8 ^ (sr & 7)) * 8));
        *reinterpret_cast<bf16x8*>(dst + (size_t)(it * 16 + sr) * 64 + d8 * 8) = v;
      }
      MEMFENCE;   // vector reads done before next it overwrites Tw
    }
  } else {
    // V^T: block transpose [128 n][64 m] (pad->72) in two m-passes.
    for (int pass = 0; pass < 2; ++pass) {
      if ((wm >> 6) == pass) {
        for (int it = 0; it < 4; ++it)
          for (int jt = 0; jt < 4; ++jt)
            for (int r = 0; r < 4; ++r) {
              const int n = wn + jt * 16 + lo;
              const int m = it * 16 + quad * 4 + r;   // local 0..63
              smem[n * 72 + (((m >> 3) ^ (n & 7)) * 8) + (m & 7)] =
                  f2bf(acc[it][jt][r] + bb[jt]);
            }
      }
      __syncthreads();
      for (int rd = 0; rd < 4; ++rd) {
        const int n = (tid >> 3) + rd * 32, m8 = tid & 7;
        bf16x8 v = *reinterpret_cast<const bf16x8*>(smem + n * 72 + ((m8 ^ (n & 7)) * 8));
        const int ng = n0 + n, h = ng >> 6, d = ng & 63;
        const int s = (m0 & 2047) + pass * 64 + m8 * 8;
        *reinterpret_cast<bf16x8*>(VTb + ((size_t)(b * 16 + h) * 64 + d) * 2048 + s) = v;
      }
      __syncthreads();
    }
  }
}

// ---------------------------------------------------------------- attention
// R4: R0's proven tile core (K/V glds16-staged, Pt round-trip, same swizzles)
// reshaped from 128q-blocks/512 to 64q-blocks/1024. Each wave owns ONE qset
// (16 q) instead of two; LDS 48->40KB (Pt halves) -> 4 blocks/CU x 4 waves =
// 16 waves/CU, all 1024 blocks co-resident (1024 = 4x256 exactly). Evidence
// (R0/R1/R2): all pipes <45% busy, latency-chain bound, grid-capped at
// 2 blocks/CU; R3 proved registers can't hold more state (spill disaster).
// This doubles resident waves at unchanged per-wave register/LDS shape.
// Balance: qi = perm[j], perm octets {r, 15-r, 16+r, 31-r} -> any CU's 4
// blocks (j, j+8, j+16, j+24 under round-robin) sum to exactly 66 tiles;
// longest items dispatch first. Masking: diagonal tile = (kt==qi), no skip.
__global__ __launch_bounds__(256, 4) void attn(
    const u16* __restrict__ Qb, const u16* __restrict__ Kb,
    const u16* __restrict__ VTb, float* __restrict__ out) {
  __shared__ __attribute__((aligned(16))) u16 Ks[2][64 * 64];   // [key][d] swz
  __shared__ __attribute__((aligned(16))) u16 Vs[2][64 * 64];   // [d][key] swz
  __shared__ __attribute__((aligned(16))) u16 Pt[4][16 * 64];   // per-wave

  const int L = blockIdx.x;                 // 1024 blocks
  const int bh = L & 31;                    // bh%8 = L%8 -> 4 bh per XCD (L2)
  const int j = L >> 5;                     // 0..31
  const int g = j >> 3, r = j & 7;
  const int qi = (g == 0) ? r : (g == 1) ? 15 - r : (g == 2) ? 16 + r : 31 - r;
  const int kstart = qi;                    // diagonal 64-key tile

  const int tid = threadIdx.x, w = tid >> 6, lane = tid & 63;
  const int lo = lane & 15, quad = lane >> 4;

  const u16* Qh = Qb + (size_t)bh * (2048 * 64);
  const u16* Kh = Kb + (size_t)bh * (2048 * 64);
  const u16* Vh = VTb + (size_t)bh * (64 * 2048);

  const int qrow = qi * 64 + w * 16 + lo;
  bf16x8 qf[2];
  qf[0] = *reinterpret_cast<const bf16x8*>(Qh + (size_t)qrow * 64 + quad * 8);
  qf[1] = *reinterpret_cast<const bf16x8*>(Qh + (size_t)qrow * 64 + 32 + quad * 8);

  float lrun = 0.f;
  floatx4 acc[4];
  for (int dt = 0; dt < 4; ++dt) acc[dt] = (floatx4)0.f;

  const int srow8 = lane >> 3, sblk = lane & 7;
  const int sswz = (sblk ^ srow8) * 8;          // staging XOR swizzle

  for (int jj = 0; jj < 2; ++jj) {   // prologue: stage tile kstart into buf 0
    const int b8 = (w * 2 + jj) * 8;
    glds16(&Ks[0][b8 * 64], Kh + (size_t)(kstart * 64 + b8 + srow8) * 64 + sswz);
    glds16(&Vs[0][b8 * 64], Vh + (size_t)(b8 + srow8) * 2048 + kstart * 64 + sswz);
  }
  __syncthreads();

  for (int kt = kstart; kt < 32; ++kt) {
    const int cur = (kt - kstart) & 1, nxt = cur ^ 1;
    if (kt < 31)   // prefetch next tile before compute
      for (int jj = 0; jj < 2; ++jj) {
        const int b8 = (w * 2 + jj) * 8;
        glds16(&Ks[nxt][b8 * 64], Kh + (size_t)((kt + 1) * 64 + b8 + srow8) * 64 + sswz);
        glds16(&Vs[nxt][b8 * 64], Vh + (size_t)(b8 + srow8) * 2048 + (kt + 1) * 64 + sswz);
      }
    const u16* ksb = Ks[cur];
    const u16* vsb = Vs[cur];

    const bool maskp = (kt == kstart);   // only the diagonal tile masks

    floatx4 sc[4];
    for (int t = 0; t < 4; ++t) sc[t] = (floatx4)0.f;
    for (int kk = 0; kk < 2; ++kk) {
      const int swz = ((kk * 4 + quad) ^ (lo & 7)) * 8;
      for (int t = 0; t < 4; ++t) {
        bf16x8 ka = *reinterpret_cast<const bf16x8*>(ksb + (t * 16 + lo) * 64 + swz);
        sc[t] = MFMA16(ka, qf[kk], sc[t]);
      }
    }

    u16* ptw = &Pt[w][0];
    for (int t = 0; t < 4; ++t) {
      float p0 = EXP2(sc[t][0]), p1 = EXP2(sc[t][1]);
      float p2 = EXP2(sc[t][2]), p3 = EXP2(sc[t][3]);
      if (maskp) {   // keep key > q (faithful buggy mask)
        const int key = kt * 64 + t * 16 + quad * 4;
        p0 = (key + 0 > qrow) ? p0 : 0.f;
        p1 = (key + 1 > qrow) ? p1 : 0.f;
        p2 = (key + 2 > qrow) ? p2 : 0.f;
        p3 = (key + 3 > qrow) ? p3 : 0.f;
      }
      lrun += (p0 + p1) + (p2 + p3);
      ushort4 pk;   // short-family store: aliases the bf16x8 read below
      pk.x = f2bf_hu(p0); pk.y = f2bf_hu(p1);
      pk.z = f2bf_hu(p2); pk.w = f2bf_hu(p3);
      u16* pdst = ptw + lo * 64 +
                  (((2 * t + (quad >> 1)) ^ (lo & 7)) * 8) + (quad & 1) * 4;
      *reinterpret_cast<ushort4*>(pdst) = pk;
    }
    MEMFENCE;   // Pt writes ordered before PV reads (same wave, in-order DS)

    for (int kk = 0; kk < 2; ++kk) {   // O^T += V^T * P^T
      const int pswz = ((kk * 4 + quad) ^ (lo & 7)) * 8;
      bf16x8 pb = *reinterpret_cast<const bf16x8*>(ptw + lo * 64 + pswz);
      for (int dt = 0; dt < 4; ++dt) {
        bf16x8 va = *reinterpret_cast<const bf16x8*>(vsb + (dt * 16 + lo) * 64 + pswz);
        acc[dt] = MFMA16(va, pb, acc[dt]);
      }
    }
    MEMFENCE;   // Pt reads done before next tile overwrites (same wave)
    __syncthreads();   // staging of nxt complete + all waves done with cur
  }

  const int b = bh >> 4, hh = bh & 15;
  float l = lrun;
  l += __shfl_xor(l, 16);
  l += __shfl_xor(l, 32);
  if (l != 0.f) {     // l==0 only for fully-masked row 2047 (fix2047)
    const float rl = 1.f / l;
    float* op = out + ((size_t)(b * 2048 + qrow)) * 1024 + hh * 64 + quad * 4;
    for (int dt = 0; dt < 4; ++dt) {
      float4 o4;
      o4.x = acc[dt][0] * rl; o4.y = acc[dt][1] * rl;
      o4.z = acc[dt][2] * rl; o4.w = acc[dt][3] * rl;
      *reinterpret_cast<float4*>(op + dt * 16) = o4;
    }
  }
}

// ---------------------------------------------------------------- fix2047
// Row 2047 fully masked -> uniform softmax: out = mean_s V[b,s,:].
__global__ __launch_bounds__(256) void fix2047(const u16* __restrict__ VTb,
                                               float* __restrict__ out) {
  const int bh = blockIdx.x;
  const u16* Vh = VTb + (size_t)bh * (64 * 2048);
  const int t = threadIdx.x;
  const int d = t >> 2, j = t & 3;
  float s = 0.f;
  const u16* row = Vh + (size_t)d * 2048 + j * 512;
  for (int i = 0; i < 64; ++i) {
    bf16x8 v = *reinterpret_cast<const bf16x8*>(row + i * 8);
    for (int e = 0; e < 8; ++e) s += bf2f((u16)v[e]);
  }
  s += __shfl_xor(s, 1);
  s += __shfl_xor(s, 2);
  if (j == 0) {
    const int b = bh >> 4, h = bh & 15;
    out[((size_t)(b * 2048 + 2047)) * 1024 + h * 64 + d] = s * (1.f / 2048.f);
  }
}

// ---------------------------------------------------------------- launch
extern "C" void kernel_launch(void* const* d_in, const int* in_sizes, int n_in,
                              void* d_out, int out_size, void* d_ws, size_t ws_size,
                              hipStream_t stream) {
  const float* x  = (const float*)d_in[0];
  const float* Wq = (const float*)d_in[1];
  const float* bq = (const float*)d_in[2];
  const float* Wk = (const float*)d_in[3];
  const float* bk = (const float*)d_in[4];
  const float* Wv = (const float*)d_in[5];
  const float* bv = (const float*)d_in[6];
  float* out = (float*)d_out;

  char* ws = (char*)d_ws;
  u16* xb  = (u16*)(ws);                  // 8 MB: x as bf16 [4096][1024]
  u16* Wb  = (u16*)(ws + (8u << 20));     // 6 MB: Wq,Wk,Wv bf16
  u16* Qb  = (u16*)(ws + (14u << 20));    // 8 MB: Q  [B,H,S,dh] (pre-scaled)
  u16* Kb  = (u16*)(ws + (22u << 20));    // 8 MB: K  [B,H,S,dh]
  u16* VTb = (u16*)(ws + (30u << 20));    // 8 MB: V^T [B,H,dh,S]

  cvt_all<<<7168, 256, 0, stream>>>(x, Wq, Wk, Wv, xb, Wb);
  qkv_gemm<<<dim3(32, 8, 3), 256, 0, stream>>>(xb, Wb, bq, bk, bv, Qb, Kb, VTb);
  attn<<<dim3(1024), 256, 0, stream>>>(Qb, Kb, VTb, out);
  fix2047<<<dim3(32), 256, 0, stream>>>(VTb, out);
}